// Round 1
// 232.073 us; speedup vs baseline: 1.0047x; 1.0047x over previous
//
#include <hip/hip_runtime.h>

// Problem constants (fixed by setup_inputs): B=128, C=3, N=320
constexpr int B    = 128;
constexpr int C    = 3;
constexpr int N    = 320;
constexpr int G    = N * N;        // 102400 elements per (b, c) plane
constexpr int G4   = G / 4;        // 25600 float4 chunks per plane
constexpr int ROW4 = N / 4;        // 80 float4 chunks per row
// Round 5: 4x more blocks, ITERS 8 -> 2. Each thread issues ALL 8 vector
// loads up front (two batches x {3 planes + target}) -> one vmcnt wait,
// zero dependent load->consume chain, 4x the resident-wave population.
// Theory: prior kernel was latency/TLP-bound at ~2.5 TB/s, not BW-bound.
constexpr int BLOCKS  = 6400;      // 6400*256 = 1,638,400 = 64 * G4 -> q invariant per thread
constexpr int THREADS = 256;
constexpr int BSTEP   = (BLOCKS * THREADS) / G4;  // 64 batches covered per sweep
constexpr int ITERS   = B / BSTEP;                // 2 (exact)
static_assert(BSTEP * G4 == BLOCKS * THREADS, "grid must tile planes exactly");
static_assert(ITERS * BSTEP == B, "batches must divide exactly");
constexpr unsigned long long TOTAL_EDGES =
    (unsigned long long)B * (unsigned long long)(N * (N - 1) / 2); // 6,533,120

// first-occurrence argmax over C=3 (matches jnp.argmax tie rule), masked by
// the strict-upper-triangle lane masks m0..m2 (4th lane is always valid when
// the chunk passed the jb+3 > i test).
__device__ __forceinline__ unsigned edge_hits(
    const float4& x0, const float4& x1, const float4& x2, const int4& tv,
    unsigned m0, unsigned m1, unsigned m2)
{
    unsigned c = 0;
    { int pred = 0; float m = x0.x;
      if (x1.x > m) { m = x1.x; pred = 1; }
      if (x2.x > m) { pred = 2; }
      c += m0 & (unsigned)(pred == tv.x); }
    { int pred = 0; float m = x0.y;
      if (x1.y > m) { m = x1.y; pred = 1; }
      if (x2.y > m) { pred = 2; }
      c += m1 & (unsigned)(pred == tv.y); }
    { int pred = 0; float m = x0.z;
      if (x1.z > m) { m = x1.z; pred = 1; }
      if (x2.z > m) { pred = 2; }
      c += m2 & (unsigned)(pred == tv.z); }
    { int pred = 0; float m = x0.w;
      if (x1.w > m) { m = x1.w; pred = 1; }
      if (x2.w > m) { pred = 2; }
      c += (unsigned)(pred == tv.w); }   // jb+3 > i guaranteed by the chunk test
    return c;
}

// __launch_bounds__(256, 4): <=128 VGPRs; we need ~64 (8 in-flight float4/int4
// payloads + addresses). 4 waves/SIMD = 16 waves/CU.
__global__ __launch_bounds__(THREADS, 4) void edge_acc_kernel(
    const float* __restrict__ inp,       // [B, C, G] float32
    const int*   __restrict__ tgt,       // [B, G] int32
    unsigned int* __restrict__ partials) // [BLOCKS], plain stores (no init needed)
{
    const int tid = blockIdx.x * THREADS + threadIdx.x;   // 0 .. 1,638,399
    const int q   = tid % G4;            // chunk within a plane (loop-invariant)
    const int b0  = tid / G4;            // 0 .. 63
    const int i   = q / ROW4;            // row in N x N
    const int jb  = (q - i * ROW4) * 4;  // first column of this chunk

    unsigned int cnt = 0;

    // Strict upper triangle: j > i. Whole-chunk skip decided ONCE per thread;
    // ~48% of threads (entire lower-triangle blocks) issue no loads at all.
    if (jb + 3 > i) {
        const unsigned m0 = (unsigned)(jb + 0 > i);
        const unsigned m1 = (unsigned)(jb + 1 > i);
        const unsigned m2 = (unsigned)(jb + 2 > i);
        const size_t gofs  = (size_t)q * 4;

        const float* pA = inp + gofs + (size_t)b0 * (C * G);            // batch b0
        const float* pB = pA + (size_t)BSTEP * (C * G);                 // batch b0+64
        const int*   tA = tgt + gofs + (size_t)b0 * G;
        const int*   tB = tA + (size_t)BSTEP * G;

        // All 8 vector loads issued back-to-back: 8 x 16 B/lane in flight,
        // a single implicit vmcnt wait before the first consume.
        const float4 a0 = *(const float4*)(pA);
        const float4 a1 = *(const float4*)(pA + G);
        const float4 a2 = *(const float4*)(pA + 2 * G);
        const int4   ta = *(const int4*)(tA);
        const float4 c0 = *(const float4*)(pB);
        const float4 c1 = *(const float4*)(pB + G);
        const float4 c2 = *(const float4*)(pB + 2 * G);
        const int4   tb = *(const int4*)(tB);

        cnt  = edge_hits(a0, a1, a2, ta, m0, m1, m2);
        cnt += edge_hits(c0, c1, c2, tb, m0, m1, m2);
    }

    // ---- wave (64-lane shuffle) -> block (LDS) -> one plain store per block ----
    #pragma unroll
    for (int off = 32; off > 0; off >>= 1)
        cnt += __shfl_down(cnt, off, 64);

    __shared__ unsigned int wsum[THREADS / 64];
    const int lane = threadIdx.x & 63;
    const int wave = threadIdx.x >> 6;
    if (lane == 0) wsum[wave] = cnt;
    __syncthreads();

    if (threadIdx.x == 0)
        partials[blockIdx.x] = wsum[0] + wsum[1] + wsum[2] + wsum[3];
}

// 256-thread finalize (BLOCKS grew 4x): uint4 partial reads, wave shuffle +
// tiny LDS combine, one store.
__global__ __launch_bounds__(256) void finalize_kernel(
    const unsigned int* __restrict__ partials,  // [BLOCKS], BLOCKS % 4 == 0
    float* __restrict__ out)
{
    unsigned int s = 0;
    const uint4* p4 = (const uint4*)partials;
    for (int idx = threadIdx.x; idx < BLOCKS / 4; idx += 256) {
        const uint4 v = p4[idx];
        s += v.x + v.y + v.z + v.w;
    }

    #pragma unroll
    for (int off = 32; off > 0; off >>= 1)
        s += __shfl_down(s, off, 64);

    __shared__ unsigned int wsum[4];
    const int lane = threadIdx.x & 63;
    const int wave = threadIdx.x >> 6;
    if (lane == 0) wsum[wave] = s;
    __syncthreads();

    if (threadIdx.x == 0) {
        const unsigned int total = wsum[0] + wsum[1] + wsum[2] + wsum[3];
        out[0] = 1.0f - (float)((double)total / (double)TOTAL_EDGES);
    }
}

extern "C" void kernel_launch(void* const* d_in, const int* in_sizes, int n_in,
                              void* d_out, int out_size, void* d_ws, size_t ws_size,
                              hipStream_t stream) {
    const float* inp = (const float*)d_in[0];
    const int*   tgt = (const int*)d_in[1];
    float*       out = (float*)d_out;
    unsigned int* partials = (unsigned int*)d_ws;  // BLOCKS * 4 = 25,600 bytes used

    edge_acc_kernel<<<BLOCKS, THREADS, 0, stream>>>(inp, tgt, partials);
    finalize_kernel<<<1, 256, 0, stream>>>(partials, out);
}